// Round 1
// baseline (339.383 us; speedup 1.0000x reference)
//
#include <hip/hip_runtime.h>

// VIF SSIM loss: per-11x11-block stats of three f32 images, SSIM score, mean.
// History: R1-R4 converged on a no-spill datapath (VGPR 76, 16.9KB LDS,
// float4 accumulators, end-of-loop l/r fold) at 128us profiled / 336us timed.
// R5 diagnosis: warm-L3 replay (65KB HBM traffic) ran in the SAME 128us as
// cold (190MB) -> duration is independent of data movement. The fixed cost is
// the 2048 device-scope atomicAdd(double) ops to ONE address (~62ns each
// serialized ~= 128us; ~150ns when the line is re-dirtied by the per-iteration
// memset ~= the 336us timed figure). Streaming itself already ran at ~6.3TB/s
// combined HBM+L3 during the work phase.
// R5 fix: no atomics at all. Each block stores its score-sum to
// partials[blockIdx.x] (2048 doubles in d_ws, every slot written every launch
// -> no memset dispatch either); finalize is a 1-wave tree reduce.

namespace {
constexpr int K      = 11;
constexpr int W      = 1408;
constexpr int H      = 1408;
constexpr int B      = 16;
constexpr int BPR    = W / K;   // 128 blocks per row
constexpr int BROWS  = H / K;   // 128 block rows
constexpr int CHUNKS = W / 4;   // 352 float4 chunks per image row
constexpr int NWG    = B * BROWS; // 2048 workgroups in pass1
constexpr float C_C  = 0.0009f;
constexpr float INV_KK = 1.0f / (float)(K * K);
}

__device__ __forceinline__ void acc4(float4& a, const float4 v) {
    a.x += v.x; a.y += v.y; a.z += v.z; a.w += v.w;
}
__device__ __forceinline__ void fma4(float4& a, const float4 u, const float4 v) {
    a.x += u.x * v.x; a.y += u.y * v.y; a.z += u.z * v.z; a.w += u.w * v.w;
}

// Split a float4 column-sum into left-block / right-block contributions.
// nb = #leading components belonging to the left block (1..11; >=4 => all left).
__device__ __forceinline__ void split4(const float4 a, const int nb,
                                       float& l, float& r) {
    l = a.x;
    r = 0.f;
    if (nb > 1) l += a.y; else r += a.y;
    if (nb > 2) l += a.z; else r += a.z;
    if (nb > 3) l += a.w; else r += a.w;
}

// NOTE: no min-waves arg! (,6) clamps VGPR to 40 and spills ~1GB (R2/R3).
__global__ __launch_bounds__(384) void vif_pass1(
    const float* __restrict__ vis,
    const float* __restrict__ ir,
    const float* __restrict__ fus,
    double* __restrict__ partials)
{
    // Per-BLOCK partial sums: 8 quantities x 4 slots x 128 blocks = 16 KB.
    // Slot = chunk&3: the <=4 consecutive chunks overlapping a block get
    // distinct slots -> no atomics, deterministic (verified R2/R3, absmax 0).
    __shared__ float s[8][4][BPR];
    __shared__ float wsum[6];

    const int t  = threadIdx.x;
    const int b  = blockIdx.x >> 7;    // batch (grid = B*BROWS, BROWS=128)
    const int br = blockIdx.x & 127;   // block row

    // Zero the partial-sum LDS (slots not covered by any chunk stay 0).
    for (int i = t; i < 8 * 4 * BPR; i += 384) ((float*)s)[i] = 0.f;
    __syncthreads();

    if (t < CHUNKS) {
        const size_t base = (size_t)b * ((size_t)H * W) + (size_t)br * K * W
                          + (size_t)t * 4;
        float4 sv  = make_float4(0.f, 0.f, 0.f, 0.f);
        float4 sv2 = make_float4(0.f, 0.f, 0.f, 0.f);
        float4 si  = make_float4(0.f, 0.f, 0.f, 0.f);
        float4 si2 = make_float4(0.f, 0.f, 0.f, 0.f);
        float4 sf  = make_float4(0.f, 0.f, 0.f, 0.f);
        float4 sf2 = make_float4(0.f, 0.f, 0.f, 0.f);
        float4 svf = make_float4(0.f, 0.f, 0.f, 0.f);
        float4 sif = make_float4(0.f, 0.f, 0.f, 0.f);
#pragma unroll
        for (int r = 0; r < K; ++r) {
            const size_t o = base + (size_t)r * W;
            const float4 v = *(const float4*)(vis + o);
            const float4 i = *(const float4*)(ir  + o);
            const float4 f = *(const float4*)(fus + o);
            acc4(sv, v);
            fma4(sv2, v, v);
            acc4(si, i);
            fma4(si2, i, i);
            acc4(sf, f);
            fma4(sf2, f, f);
            fma4(svf, v, f);
            fma4(sif, i, f);
        }
        // Fold the 4 columns into per-block contributions (once, not per-row).
        const int bl = (4 * t) / K;            // left block index
        const int nb = K * (bl + 1) - 4 * t;   // #cols in left block
        const int sl = t & 3;
        float l, r;
        split4(sv,  nb, l, r); s[0][sl][bl] = l; if (nb < 4) s[0][sl][bl + 1] = r;
        split4(sv2, nb, l, r); s[1][sl][bl] = l; if (nb < 4) s[1][sl][bl + 1] = r;
        split4(si,  nb, l, r); s[2][sl][bl] = l; if (nb < 4) s[2][sl][bl + 1] = r;
        split4(si2, nb, l, r); s[3][sl][bl] = l; if (nb < 4) s[3][sl][bl + 1] = r;
        split4(sf,  nb, l, r); s[4][sl][bl] = l; if (nb < 4) s[4][sl][bl + 1] = r;
        split4(sf2, nb, l, r); s[5][sl][bl] = l; if (nb < 4) s[5][sl][bl + 1] = r;
        split4(svf, nb, l, r); s[6][sl][bl] = l; if (nb < 4) s[6][sl][bl + 1] = r;
        split4(sif, nb, l, r); s[7][sl][bl] = l; if (nb < 4) s[7][sl][bl + 1] = r;
    }
    __syncthreads();

    // ---- Phase 2: fold 4 slots per block, compute score ----
    float score = 0.0f;
    if (t < BPR) {
        float a[8];
#pragma unroll
        for (int q = 0; q < 8; ++q)   // lane-consecutive reads: conflict-free
            a[q] = s[q][0][t] + s[q][1][t] + s[q][2][t] + s[q][3][t];

        const float vm  = a[0] * INV_KK;
        const float vs2 = a[1] * INV_KK;
        const float im  = a[2] * INV_KK;
        const float is2 = a[3] * INV_KK;
        const float fm  = a[4] * INV_KK;
        const float fs2 = a[5] * INV_KK;
        const float vfm = a[6] * INV_KK;
        const float ifm = a[7] * INV_KK;

        const float vv = fabsf(vs2 - vm * vm);
        const float iv = fabsf(is2 - im * im);
        const float fv = fabsf(fs2 - fm * fm);
        const float vf_cov = vfm - vm * fm;
        const float if_cov = ifm - im * fm;

        const float l_vf = (2.f * vm * fm + C_C) / (vm * vm + fm * fm + C_C);
        const float l_if = (2.f * im * fm + C_C) / (im * im + fm * fm + C_C);
        const float s_vf = (vf_cov + C_C) / (vv + fv + C_C);
        const float s_if = (if_cov + C_C) / (iv + fv + C_C);

        score = (vm > im) ? (l_vf * s_vf) : (l_if * s_if);
    }

    // ---- Reduce scores across the workgroup -> ONE PLAIN STORE (no atomic) ----
#pragma unroll
    for (int o = 32; o > 0; o >>= 1) score += __shfl_down(score, o, 64);
    if ((t & 63) == 0) wsum[t >> 6] = score;
    __syncthreads();
    if (t == 0) {
        float tot = 0.f;
#pragma unroll
        for (int wv = 0; wv < 6; ++wv) tot += wsum[wv];
        partials[blockIdx.x] = (double)tot;   // distinct slot per block
    }
}

__global__ __launch_bounds__(64) void vif_finalize(
    const double* __restrict__ partials,
    float* __restrict__ out)
{
    const int t = threadIdx.x;
    double s = 0.0;
    // 2048 doubles, lane-consecutive strided reads: coalesced.
    for (int i = t; i < NWG; i += 64) s += partials[i];
#pragma unroll
    for (int o = 32; o > 0; o >>= 1) s += __shfl_down(s, o, 64);
    if (t == 0) {
        out[0] = 1.0f - (float)(s / (double)(B * BROWS * BPR));
    }
}

extern "C" void kernel_launch(void* const* d_in, const int* in_sizes, int n_in,
                              void* d_out, int out_size, void* d_ws, size_t ws_size,
                              hipStream_t stream) {
    const float* vis = (const float*)d_in[0];
    const float* ir  = (const float*)d_in[1];
    const float* fus = (const float*)d_in[2];
    float* out = (float*)d_out;
    double* partials = (double*)d_ws;   // 2048 * 8B = 16 KB of workspace

    // No memset needed: every partials slot is written by pass1 every launch
    // (d_ws poison is fully overwritten), and out is written by finalize.
    vif_pass1<<<dim3(NWG), dim3(384), 0, stream>>>(vis, ir, fus, partials);
    vif_finalize<<<dim3(1), dim3(64), 0, stream>>>(partials, out);
}